// Round 1
// baseline (656.569 us; speedup 1.0000x reference)
//
#include <hip/hip_runtime.h>
#include <hip/hip_bf16.h>

#define B_ 2
#define N_ 2048
#define D_ 1024
#define H_ 16
#define DH_ 64
#define M_ 4096
#define FFI_ 4096

typedef __attribute__((ext_vector_type(8))) short bh8;
typedef __attribute__((ext_vector_type(4))) float f4;

#define DEV static __device__ __forceinline__

DEV short f2bf(float f) { __hip_bfloat16 h = __float2bfloat16(f); return *reinterpret_cast<short*>(&h); }
DEV float bf2f(short s) { __hip_bfloat16 h = *reinterpret_cast<__hip_bfloat16*>(&s); return __bfloat162float(h); }

#define GLDS(gp, lp) __builtin_amdgcn_global_load_lds((const __attribute__((address_space(1))) void*)(gp), (__attribute__((address_space(3))) void*)(lp), 16, 0, 0)
#define MFMA16(a,b,c) __builtin_amdgcn_mfma_f32_16x16x32_bf16(a,b,c,0,0,0)

// ---------------- LayerNorm: fp32 in -> fp32 out (optional) + bf16 out ----------------
__global__ __launch_bounds__(256) void ln_kernel(const float* __restrict__ x,
    const float* __restrict__ g, const float* __restrict__ b,
    float* __restrict__ outF, short* __restrict__ outB)
{
  const int row = blockIdx.x;
  const int t = threadIdx.x;
  const float4 v = reinterpret_cast<const float4*>(x + (long)row*D_)[t];
  float s = v.x+v.y+v.z+v.w;
  float sq = v.x*v.x+v.y*v.y+v.z*v.z+v.w*v.w;
  #pragma unroll
  for (int o=32;o>0;o>>=1){ s += __shfl_xor(s,o); sq += __shfl_xor(sq,o); }
  __shared__ float red[8];
  const int w = t>>6, l = t&63;
  if (l==0){ red[w]=s; red[4+w]=sq; }
  __syncthreads();
  s  = red[0]+red[1]+red[2]+red[3];
  sq = red[4]+red[5]+red[6]+red[7];
  const float mu = s*(1.f/D_);
  const float rstd = rsqrtf(sq*(1.f/D_) - mu*mu + 1e-5f);
  const float4 gv = reinterpret_cast<const float4*>(g)[t];
  const float4 bv = reinterpret_cast<const float4*>(b)[t];
  float4 y;
  y.x=(v.x-mu)*rstd*gv.x+bv.x; y.y=(v.y-mu)*rstd*gv.y+bv.y;
  y.z=(v.z-mu)*rstd*gv.z+bv.z; y.w=(v.w-mu)*rstd*gv.w+bv.w;
  if (outF) reinterpret_cast<float4*>(outF + (long)row*D_)[t] = y;
  short4 ys; ys.x=f2bf(y.x); ys.y=f2bf(y.y); ys.z=f2bf(y.z); ys.w=f2bf(y.w);
  reinterpret_cast<short4*>(outB + (long)row*D_)[t] = ys;
}

// ---------------- transpose + fp32->bf16 cast: in R x C -> out C x R ----------------
__global__ __launch_bounds__(256) void transpose_cast(const float* __restrict__ in,
    short* __restrict__ out, int R, int C)
{
  __shared__ float tile[32][33];
  const int tx = threadIdx.x & 31, ty = threadIdx.x >> 5;
  const int c0 = blockIdx.x*32, r0 = blockIdx.y*32;
  #pragma unroll
  for (int i=0;i<4;i++) tile[ty+i*8][tx] = in[(long)(r0+ty+i*8)*C + c0+tx];
  __syncthreads();
  #pragma unroll
  for (int i=0;i<4;i++) out[(long)(c0+ty+i*8)*R + r0+tx] = f2bf(tile[tx][ty+i*8]);
}

// ---------------- GEMM core: C(128x128) = A(MxK) * BT(NxK)^T, bf16 MFMA ----------------
DEV void gemm_core(const short* __restrict__ A, const short* __restrict__ BT, int K,
                   int m0, int n0, short* lA, short* lB, f4 (&acc)[4][4])
{
  const int t = threadIdx.x, w = t>>6, l = t&63;
  const int wrow = (w>>1)*64, wcol = (w&1)*64;
  const int lr = l&15, lk = (l>>4)*8;
  const int sr = t>>2, sc = (t&3)*8;
  const short* gA = A  + (long)(m0+sr)*K + sc;
  const short* gB = BT + (long)(n0+sr)*K + sc;
  #pragma unroll
  for (int i=0;i<4;i++)
    #pragma unroll
    for (int j=0;j<4;j++) acc[i][j] = f4{0.f,0.f,0.f,0.f};
  for (int k0=0; k0<K; k0+=32) {
    __syncthreads();
    GLDS(gA,              &lA[w*512]);
    GLDS(gA + (long)64*K, &lA[2048 + w*512]);
    GLDS(gB,              &lB[w*512]);
    GLDS(gB + (long)64*K, &lB[2048 + w*512]);
    gA += 32; gB += 32;
    asm volatile("s_waitcnt vmcnt(0)" ::: "memory");
    __syncthreads();
    bh8 af[4], bf_[4];
    #pragma unroll
    for (int i=0;i<4;i++) af[i]  = *reinterpret_cast<const bh8*>(&lA[(wrow+i*16+lr)*32 + lk]);
    #pragma unroll
    for (int j=0;j<4;j++) bf_[j] = *reinterpret_cast<const bh8*>(&lB[(wcol+j*16+lr)*32 + lk]);
    #pragma unroll
    for (int i=0;i<4;i++)
      #pragma unroll
      for (int j=0;j<4;j++)
        acc[i][j] = MFMA16(af[i], bf_[j], acc[i][j]);
  }
}

// ---------------- fused QKV GEMM: writes fp32 (B*H,N,DH) outputs + bf16 ws copies ----------------
__global__ __launch_bounds__(256) void gemm_qkv(const short* __restrict__ A,
    const short* __restrict__ BTq, const short* __restrict__ BTk, const short* __restrict__ BTv,
    float* __restrict__ oQ, float* __restrict__ oK, float* __restrict__ oV,
    short* __restrict__ bQ, short* __restrict__ bK, short* __restrict__ bV)
{
  __shared__ short lA[4096], lB[4096];
  const int m0 = blockIdx.x*128;
  const int by = blockIdx.y, sel = by>>3, n0 = (by&7)*128;
  const short* BT = sel==0 ? BTq : (sel==1 ? BTk : BTv);
  float* oF = sel==0 ? oQ : (sel==1 ? oK : oV);
  short* oB = sel==0 ? bQ : (sel==1 ? bK : bV);
  const float bscale = sel==0 ? 0.125f : 1.0f;   // pre-scale Q by DH^-0.5 (exact pow2)
  f4 acc[4][4];
  gemm_core(A, BT, 1024, m0, n0, lA, lB, acc);
  const int t = threadIdx.x, w = t>>6, l = t&63;
  const int wrow=(w>>1)*64, wcol=(w&1)*64, lr=l&15;
  #pragma unroll
  for (int i=0;i<4;i++)
    #pragma unroll
    for (int j=0;j<4;j++)
      #pragma unroll
      for (int r=0;r<4;r++) {
        const int grow = m0 + wrow + i*16 + (l>>4)*4 + r;
        const int gcol = n0 + wcol + j*16 + lr;
        const int bb = grow >> 11, nn = grow & 2047;
        const int hh = gcol >> 6, dd = gcol & 63;
        const long oi = ((long)(bb*H_ + hh)*N_ + nn)*DH_ + dd;
        const float v = acc[i][j][r];
        oF[oi] = v;
        oB[oi] = f2bf(v * bscale);
      }
}

// ---------------- generic GEMM epilogues: 1 = +bias+resid -> f32, 2 = +bias -> bf16 ----------------
template<int MODE>
__global__ __launch_bounds__(256) void gemm_bt(const short* __restrict__ A,
    const short* __restrict__ BT, int Ndim, int K,
    const float* __restrict__ bias, const float* __restrict__ resid,
    float* __restrict__ outF, short* __restrict__ outB)
{
  __shared__ short lA[4096], lB[4096];
  const int m0 = blockIdx.x*128, n0 = blockIdx.y*128;
  f4 acc[4][4];
  gemm_core(A, BT, K, m0, n0, lA, lB, acc);
  const int t = threadIdx.x, w=t>>6, l=t&63;
  const int wrow=(w>>1)*64, wcol=(w&1)*64, lr=l&15;
  #pragma unroll
  for (int i=0;i<4;i++)
    #pragma unroll
    for (int j=0;j<4;j++)
      #pragma unroll
      for (int r=0;r<4;r++) {
        const int grow = m0 + wrow + i*16 + (l>>4)*4 + r;
        const int gcol = n0 + wcol + j*16 + lr;
        const long oi = (long)grow*Ndim + gcol;
        const float v = acc[i][j][r] + bias[gcol];
        if (MODE==1) outF[oi] = v + resid[oi];
        else         outB[oi] = f2bf(v);
      }
}

// ---------------- flash attention: Q pre-scaled, bf16 in, fp32 inter_out + bf16 (B,N,INNER) ----------------
__global__ __launch_bounds__(256) void attn_kernel(const short* __restrict__ Q,
    const short* __restrict__ Kb, const short* __restrict__ Vb,
    float* __restrict__ interOut, short* __restrict__ attnB)
{
  __shared__ short Kt[64*72];     // K tile row-major [j][72], padded
  __shared__ short Vt[64*72];     // V tile transposed [d][72], padded
  __shared__ short Pt[4*16*72];   // per-wave P tiles, padded
  const int t = threadIdx.x, w = t>>6, l = t&63;
  const int bh = blockIdx.y;
  const int q0 = blockIdx.x*64;
  const int lr = l&15, lk = (l>>4)*8;
  const long base = (long)bh * (N_*DH_);
  const int qrow = q0 + w*16;
  bh8 qf0 = *reinterpret_cast<const bh8*>(&Q[base + (long)(qrow+lr)*DH_ + lk]);
  bh8 qf1 = *reinterpret_cast<const bh8*>(&Q[base + (long)(qrow+lr)*DH_ + 32 + lk]);
  f4 o[4];
  #pragma unroll
  for (int i=0;i<4;i++) o[i]=f4{0.f,0.f,0.f,0.f};
  float m_run[4], l_run[4];
  #pragma unroll
  for (int r=0;r<4;r++){ m_run[r]=-1e30f; l_run[r]=0.f; }
  const int srow = t>>3, sd = (t&7)*8;
  short* Pw = &Pt[w*16*72];
  for (int kt=0; kt<N_/64; kt++) {
    __syncthreads();
    #pragma unroll
    for (int it=0; it<2; it++) {
      const int j = it*32 + srow;
      const long grow = base + (long)(kt*64 + j)*DH_ + sd;
      int4 kv = *reinterpret_cast<const int4*>(&Kb[grow]);
      *reinterpret_cast<int4*>(&Kt[j*72 + sd]) = kv;
      int4 vv = *reinterpret_cast<const int4*>(&Vb[grow]);
      const short* vs = reinterpret_cast<const short*>(&vv);
      #pragma unroll
      for (int e=0;e<8;e++) Vt[(sd+e)*72 + j] = vs[e];
    }
    __syncthreads();
    // S = Q K^T  (Q pre-scaled by 0.125)
    f4 s[4];
    #pragma unroll
    for (int cb=0;cb<4;cb++) {
      bh8 kf0 = *reinterpret_cast<const bh8*>(&Kt[(cb*16+lr)*72 + lk]);
      bh8 kf1 = *reinterpret_cast<const bh8*>(&Kt[(cb*16+lr)*72 + 32 + lk]);
      f4 z = f4{0.f,0.f,0.f,0.f};
      z = MFMA16(qf0, kf0, z);
      z = MFMA16(qf1, kf1, z);
      s[cb] = z;
    }
    // online softmax (wave-parallel, 16-lane row groups)
    float mx[4];
    #pragma unroll
    for (int r=0;r<4;r++) mx[r] = fmaxf(fmaxf(s[0][r],s[1][r]), fmaxf(s[2][r],s[3][r]));
    #pragma unroll
    for (int mk=1; mk<16; mk<<=1)
      #pragma unroll
      for (int r=0;r<4;r++) mx[r] = fmaxf(mx[r], __shfl_xor(mx[r], mk));
    float rs[4];
    #pragma unroll
    for (int r=0;r<4;r++) {
      const float mn = fmaxf(m_run[r], mx[r]);
      const float al = __expf(m_run[r]-mn);
      m_run[r] = mn;
      l_run[r] *= al;
      float sum = 0.f;
      #pragma unroll
      for (int cb=0;cb<4;cb++) {
        const float pv = __expf(s[cb][r]-mn);
        sum += pv;
        Pw[((l>>4)*4 + r)*72 + cb*16 + lr] = f2bf(pv);
      }
      rs[r] = sum;
      #pragma unroll
      for (int cb=0;cb<4;cb++) o[cb][r] *= al;
    }
    #pragma unroll
    for (int mk=1; mk<16; mk<<=1)
      #pragma unroll
      for (int r=0;r<4;r++) rs[r] += __shfl_xor(rs[r], mk);
    #pragma unroll
    for (int r=0;r<4;r++) l_run[r] += rs[r];
    // P (this wave's LDS region) -> A-frags; fence wave-local write->read
    asm volatile("s_waitcnt lgkmcnt(0)" ::: "memory");
    __builtin_amdgcn_sched_barrier(0);
    bh8 pa0 = *reinterpret_cast<const bh8*>(&Pw[lr*72 + lk]);
    bh8 pa1 = *reinterpret_cast<const bh8*>(&Pw[lr*72 + 32 + lk]);
    #pragma unroll
    for (int db=0; db<4; db++) {
      bh8 vf0 = *reinterpret_cast<const bh8*>(&Vt[(db*16+lr)*72 + lk]);
      bh8 vf1 = *reinterpret_cast<const bh8*>(&Vt[(db*16+lr)*72 + 32 + lk]);
      o[db] = MFMA16(pa0, vf0, o[db]);
      o[db] = MFMA16(pa1, vf1, o[db]);
    }
  }
  const int bb = bh>>4, hh = bh&15;
  #pragma unroll
  for (int db=0; db<4; db++)
    #pragma unroll
    for (int r=0;r<4;r++) {
      const int n = qrow + (l>>4)*4 + r;
      const int d = db*16 + lr;
      const float v = o[db][r] / l_run[r];
      interOut[base + (long)n*DH_ + d] = v;
      attnB[((long)(bb*N_ + n))*D_*0 + ((long)(bb*N_ + n))*1024 + hh*DH_ + d] = f2bf(v);
    }
}

// ---------------- a * gelu(gate), bf16 ----------------
__global__ __launch_bounds__(256) void gelu_mul(const short* __restrict__ h, short* __restrict__ g)
{
  const long i = ((long)blockIdx.x*256 + threadIdx.x)*8;
  const long m = i >> 12;
  const int j = (int)(i & 4095);
  bh8 av = *reinterpret_cast<const bh8*>(&h[m*8192 + j]);
  bh8 gv = *reinterpret_cast<const bh8*>(&h[m*8192 + 4096 + j]);
  bh8 ov;
  #pragma unroll
  for (int e=0;e<8;e++) {
    const float a  = bf2f(av[e]);
    const float xg = bf2f(gv[e]);
    const float ge = 0.5f*xg*(1.f + erff(xg*0.70710678118f));
    ov[e] = f2bf(a*ge);
  }
  *reinterpret_cast<bh8*>(&g[i]) = ov;
}

extern "C" void kernel_launch(void* const* d_in, const int* in_sizes, int n_in,
                              void* d_out, int out_size, void* d_ws, size_t ws_size,
                              hipStream_t stream)
{
  const float* x    = (const float*)d_in[0];
  const float* Wq   = (const float*)d_in[1];
  const float* Wk   = (const float*)d_in[2];
  const float* Wv   = (const float*)d_in[3];
  const float* Wo   = (const float*)d_in[4];
  const float* bo   = (const float*)d_in[5];
  const float* ln1g = (const float*)d_in[6];
  const float* ln1b = (const float*)d_in[7];
  const float* ln3g = (const float*)d_in[8];
  const float* ln3b = (const float*)d_in[9];
  const float* Wff1 = (const float*)d_in[10];
  const float* bff1 = (const float*)d_in[11];
  const float* Wff2 = (const float*)d_in[12];
  const float* bff2 = (const float*)d_in[13];
  float* out = (float*)d_out;
  const long SZ = (long)M_*D_;
  float* out_x     = out;
  float* out_q     = out + SZ;
  float* out_k     = out + 2*SZ;
  float* out_v     = out + 3*SZ;
  float* out_inter = out + 4*SZ;
  float* out_xf    = out + 5*SZ;

  char* p = (char*)d_ws;
  auto alloc = [&](size_t bytes){ void* r = (void*)p; p += (bytes + 255) & ~(size_t)255; return r; };
  short* xf_bf  = (short*)alloc(SZ*2);
  short* q_bf   = (short*)alloc(SZ*2);
  short* k_bf   = (short*)alloc(SZ*2);
  short* v_bf   = (short*)alloc(SZ*2);
  short* at_bf  = (short*)alloc(SZ*2);
  float* x2     = (float*)alloc(SZ*4);
  short* x2n_bf = (short*)alloc(SZ*2);
  short* h_bf   = (short*)alloc((size_t)M_*8192*2);
  short* g_bf   = (short*)alloc((size_t)M_*4096*2);
  short* WqT    = (short*)alloc((size_t)1024*1024*2);
  short* WkT    = (short*)alloc((size_t)1024*1024*2);
  short* WvT    = (short*)alloc((size_t)1024*1024*2);
  short* WoT    = (short*)alloc((size_t)1024*1024*2);
  short* Wff1T  = (short*)alloc((size_t)8192*1024*2);
  short* Wff2T  = (short*)alloc((size_t)1024*4096*2);
  (void)in_sizes; (void)n_in; (void)out_size; (void)ws_size;

  dim3 blk(256);
  transpose_cast<<<dim3(32,32),  blk, 0, stream>>>(Wq,   WqT,   1024, 1024);
  transpose_cast<<<dim3(32,32),  blk, 0, stream>>>(Wk,   WkT,   1024, 1024);
  transpose_cast<<<dim3(32,32),  blk, 0, stream>>>(Wv,   WvT,   1024, 1024);
  transpose_cast<<<dim3(32,32),  blk, 0, stream>>>(Wo,   WoT,   1024, 1024);
  transpose_cast<<<dim3(256,32), blk, 0, stream>>>(Wff1, Wff1T, 1024, 8192);
  transpose_cast<<<dim3(32,128), blk, 0, stream>>>(Wff2, Wff2T, 4096, 1024);
  ln_kernel<<<M_, blk, 0, stream>>>(x, ln1g, ln1b, out_xf, xf_bf);
  gemm_qkv<<<dim3(32,24), blk, 0, stream>>>(xf_bf, WqT, WkT, WvT,
                                            out_q, out_k, out_v, q_bf, k_bf, v_bf);
  attn_kernel<<<dim3(32,32), blk, 0, stream>>>(q_bf, k_bf, v_bf, out_inter, at_bf);
  gemm_bt<1><<<dim3(32,8),  blk, 0, stream>>>(at_bf,  WoT,   1024, 1024, bo,   x,   x2,    nullptr);
  ln_kernel<<<M_, blk, 0, stream>>>(x2, ln3g, ln3b, nullptr, x2n_bf);
  gemm_bt<2><<<dim3(32,64), blk, 0, stream>>>(x2n_bf, Wff1T, 8192, 1024, bff1, nullptr, nullptr, h_bf);
  gelu_mul<<<8192, blk, 0, stream>>>(h_bf, g_bf);
  gemm_bt<1><<<dim3(32,8),  blk, 0, stream>>>(g_bf,   Wff2T, 1024, 4096, bff2, x2,  out_x, nullptr);
}

// Round 3
// 611.533 us; speedup vs baseline: 1.0736x; 1.0736x over previous
//
#include <hip/hip_runtime.h>
#include <hip/hip_bf16.h>

#define B_ 2
#define N_ 2048
#define D_ 1024
#define H_ 16
#define DH_ 64
#define M_ 4096
#define FFI_ 4096

typedef __attribute__((ext_vector_type(8))) short bh8;
typedef __attribute__((ext_vector_type(4))) float f4;

#define DEV static __device__ __forceinline__

DEV short f2bf(float f) { __hip_bfloat16 h = __float2bfloat16(f); return *reinterpret_cast<short*>(&h); }
DEV float bf2f(short s) { __hip_bfloat16 h = *reinterpret_cast<__hip_bfloat16*>(&s); return __bfloat162float(h); }

#define GLDS(gp, lp) __builtin_amdgcn_global_load_lds((const __attribute__((address_space(1))) void*)(gp), (__attribute__((address_space(3))) void*)(lp), 16, 0, 0)
#define MFMA16(a,b,c) __builtin_amdgcn_mfma_f32_16x16x32_bf16(a,b,c,0,0,0)

// ---------------- LayerNorm: fp32 in -> fp32 out (optional) + bf16 out ----------------
__global__ __launch_bounds__(256) void ln_kernel(const float* __restrict__ x,
    const float* __restrict__ g, const float* __restrict__ b,
    float* __restrict__ outF, short* __restrict__ outB)
{
  const int row = blockIdx.x;
  const int t = threadIdx.x;
  const float4 v = reinterpret_cast<const float4*>(x + (long)row*D_)[t];
  float s = v.x+v.y+v.z+v.w;
  float sq = v.x*v.x+v.y*v.y+v.z*v.z+v.w*v.w;
  #pragma unroll
  for (int o=32;o>0;o>>=1){ s += __shfl_xor(s,o); sq += __shfl_xor(sq,o); }
  __shared__ float red[8];
  const int w = t>>6, l = t&63;
  if (l==0){ red[w]=s; red[4+w]=sq; }
  __syncthreads();
  s  = red[0]+red[1]+red[2]+red[3];
  sq = red[4]+red[5]+red[6]+red[7];
  const float mu = s*(1.f/D_);
  const float rstd = rsqrtf(sq*(1.f/D_) - mu*mu + 1e-5f);
  const float4 gv = reinterpret_cast<const float4*>(g)[t];
  const float4 bv = reinterpret_cast<const float4*>(b)[t];
  float4 y;
  y.x=(v.x-mu)*rstd*gv.x+bv.x; y.y=(v.y-mu)*rstd*gv.y+bv.y;
  y.z=(v.z-mu)*rstd*gv.z+bv.z; y.w=(v.w-mu)*rstd*gv.w+bv.w;
  if (outF) reinterpret_cast<float4*>(outF + (long)row*D_)[t] = y;
  short4 ys; ys.x=f2bf(y.x); ys.y=f2bf(y.y); ys.z=f2bf(y.z); ys.w=f2bf(y.w);
  reinterpret_cast<short4*>(outB + (long)row*D_)[t] = ys;
}

// ---------------- transpose + fp32->bf16 cast: in R x C -> out C x R ----------------
__global__ __launch_bounds__(256) void transpose_cast(const float* __restrict__ in,
    short* __restrict__ out, int R, int C)
{
  __shared__ float tile[32][33];
  const int tx = threadIdx.x & 31, ty = threadIdx.x >> 5;
  const int c0 = blockIdx.x*32, r0 = blockIdx.y*32;
  #pragma unroll
  for (int i=0;i<4;i++) tile[ty+i*8][tx] = in[(long)(r0+ty+i*8)*C + c0+tx];
  __syncthreads();
  #pragma unroll
  for (int i=0;i<4;i++) out[(long)(c0+ty+i*8)*R + r0+tx] = f2bf(tile[tx][ty+i*8]);
}

// ---------------- GEMM core: C(128x128) = A(MxK) * BT(NxK)^T, bf16 MFMA ----------------
DEV void gemm_core(const short* __restrict__ A, const short* __restrict__ BT, int K,
                   int m0, int n0, short* lA, short* lB, f4 (&acc)[4][4])
{
  const int t = threadIdx.x, w = t>>6, l = t&63;
  const int wrow = (w>>1)*64, wcol = (w&1)*64;
  const int lr = l&15, lk = (l>>4)*8;
  const int sr = t>>2, sc = (t&3)*8;
  const short* gA = A  + (long)(m0+sr)*K + sc;
  const short* gB = BT + (long)(n0+sr)*K + sc;
  #pragma unroll
  for (int i=0;i<4;i++)
    #pragma unroll
    for (int j=0;j<4;j++) acc[i][j] = f4{0.f,0.f,0.f,0.f};
  for (int k0=0; k0<K; k0+=32) {
    __syncthreads();
    GLDS(gA,              &lA[w*512]);
    GLDS(gA + (long)64*K, &lA[2048 + w*512]);
    GLDS(gB,              &lB[w*512]);
    GLDS(gB + (long)64*K, &lB[2048 + w*512]);
    gA += 32; gB += 32;
    asm volatile("s_waitcnt vmcnt(0)" ::: "memory");
    __syncthreads();
    bh8 af[4], bf_[4];
    #pragma unroll
    for (int i=0;i<4;i++) af[i]  = *reinterpret_cast<const bh8*>(&lA[(wrow+i*16+lr)*32 + lk]);
    #pragma unroll
    for (int j=0;j<4;j++) bf_[j] = *reinterpret_cast<const bh8*>(&lB[(wcol+j*16+lr)*32 + lk]);
    #pragma unroll
    for (int i=0;i<4;i++)
      #pragma unroll
      for (int j=0;j<4;j++)
        acc[i][j] = MFMA16(af[i], bf_[j], acc[i][j]);
  }
}

// ---------------- fused QKV GEMM: writes fp32 (B*H,N,DH) outputs + bf16 ws copies ----------------
__global__ __launch_bounds__(256) void gemm_qkv(const short* __restrict__ A,
    const short* __restrict__ BTq, const short* __restrict__ BTk, const short* __restrict__ BTv,
    float* __restrict__ oQ, float* __restrict__ oK, float* __restrict__ oV,
    short* __restrict__ bQ, short* __restrict__ bK, short* __restrict__ bV)
{
  __shared__ short lA[4096], lB[4096];
  const int m0 = blockIdx.x*128;
  const int by = blockIdx.y, sel = by>>3, n0 = (by&7)*128;
  const short* BT = sel==0 ? BTq : (sel==1 ? BTk : BTv);
  float* oF = sel==0 ? oQ : (sel==1 ? oK : oV);
  short* oB = sel==0 ? bQ : (sel==1 ? bK : bV);
  const float bscale = sel==0 ? 0.125f : 1.0f;   // pre-scale Q by DH^-0.5 (exact pow2)
  f4 acc[4][4];
  gemm_core(A, BT, 1024, m0, n0, lA, lB, acc);
  const int t = threadIdx.x, w = t>>6, l = t&63;
  const int wrow=(w>>1)*64, wcol=(w&1)*64, lr=l&15;
  #pragma unroll
  for (int i=0;i<4;i++)
    #pragma unroll
    for (int j=0;j<4;j++)
      #pragma unroll
      for (int r=0;r<4;r++) {
        const int grow = m0 + wrow + i*16 + (l>>4)*4 + r;
        const int gcol = n0 + wcol + j*16 + lr;
        const int bb = grow >> 11, nn = grow & 2047;
        const int hh = gcol >> 6, dd = gcol & 63;
        const long oi = ((long)(bb*H_ + hh)*N_ + nn)*DH_ + dd;
        const float v = acc[i][j][r];
        oF[oi] = v;
        oB[oi] = f2bf(v * bscale);
      }
}

// ---------------- generic GEMM epilogues: 1 = +bias+resid -> f32, 2 = +bias -> bf16 ----------------
template<int MODE>
__global__ __launch_bounds__(256) void gemm_bt(const short* __restrict__ A,
    const short* __restrict__ BT, int Ndim, int K,
    const float* __restrict__ bias, const float* __restrict__ resid,
    float* __restrict__ outF, short* __restrict__ outB)
{
  __shared__ short lA[4096], lB[4096];
  const int m0 = blockIdx.x*128, n0 = blockIdx.y*128;
  f4 acc[4][4];
  gemm_core(A, BT, K, m0, n0, lA, lB, acc);
  const int t = threadIdx.x, w=t>>6, l=t&63;
  const int wrow=(w>>1)*64, wcol=(w&1)*64, lr=l&15;
  #pragma unroll
  for (int i=0;i<4;i++)
    #pragma unroll
    for (int j=0;j<4;j++)
      #pragma unroll
      for (int r=0;r<4;r++) {
        const int grow = m0 + wrow + i*16 + (l>>4)*4 + r;
        const int gcol = n0 + wcol + j*16 + lr;
        const long oi = (long)grow*Ndim + gcol;
        const float v = acc[i][j][r] + bias[gcol];
        if (MODE==1) outF[oi] = v + resid[oi];
        else         outB[oi] = f2bf(v);
      }
}

// ---------------- flash attention ----------------
// K staged via global_load_lds into linear [64 rows][8 chunks of 16B] with
// both-sides XOR swizzle: lds[r][c] = K[r][c ^ (r&7)]  (source pre-swizzled,
// read swizzled — rule #21).
// V staged transposed by reg-staging: Vt[d][j] with two-level chunk swizzle
// chunk(d, j>>3) = (j>>3) ^ (d&7) ^ ((d>>3)&7)  -> conflict-free phases on
// both the 8x ds_write_b16 (sd folded into bank) and the bh8 PV reads.
__global__ __launch_bounds__(256) void attn_kernel(const short* __restrict__ Q,
    const short* __restrict__ Kb, const short* __restrict__ Vb,
    float* __restrict__ interOut, short* __restrict__ attnB)
{
  __shared__ short Kt[64*64];     // 8 KiB
  __shared__ short Vt[64*64];     // 8 KiB, V^T [d][j] swizzled
  __shared__ short Pt[4*16*72];   // per-wave P tiles, padded
  const int t = threadIdx.x, w = t>>6, l = t&63;
  const int bh = blockIdx.y;
  const int q0 = blockIdx.x*64;
  const int lr = l&15, lk = (l>>4)*8, g = l>>4;
  const long base = (long)bh * (N_*DH_);
  const int qrow = q0 + w*16;
  bh8 qf0 = *reinterpret_cast<const bh8*>(&Q[base + (long)(qrow+lr)*DH_ + lk]);
  bh8 qf1 = *reinterpret_cast<const bh8*>(&Q[base + (long)(qrow+lr)*DH_ + 32 + lk]);
  f4 o[4];
  #pragma unroll
  for (int i=0;i<4;i++) o[i]=f4{0.f,0.f,0.f,0.f};
  float m_run[4], l_run[4];
  #pragma unroll
  for (int r=0;r<4;r++){ m_run[r]=-1e30f; l_run[r]=0.f; }
  short* Pw = &Pt[w*16*72];
  const char* ldsK = (const char*)Kt;
  const int beta0 = w*2048 + l*16;        // K staging: this lane's LDS byte slot
  const int srow = t>>3, sdp = t&7, sd = sdp*8;   // V staging coords
  for (int kt=0; kt<N_/64; kt++) {
    __syncthreads();
    // ---- stage K (async DMA, pre-swizzled source) ----
    {
      const char* Kg = (const char*)(Kb + base + (long)kt*64*DH_);
      #pragma unroll
      for (int i=0;i<2;i++) {
        const int beta = beta0 + i*1024;
        const int krow = beta>>7, kpch = (beta>>4)&7;
        GLDS(Kg + krow*128 + (kpch ^ (krow&7))*16, (char*)Kt + (w*2+i)*1024);
      }
    }
    // ---- stage V transposed (reg-staged, swizzled scalar writes) ----
    #pragma unroll
    for (int it=0; it<2; it++) {
      const int j = it*32 + srow;
      const int4 vv = *reinterpret_cast<const int4*>(&Vb[base + (long)(kt*64+j)*DH_ + sd]);
      const short* vs = reinterpret_cast<const short*>(&vv);
      const int cb0 = (it*4 + (srow>>3)) ^ sdp;   // (j>>3) ^ sdp, in 0..7
      const int jc  = srow & 7;                   // j&7
      #pragma unroll
      for (int e=0;e<8;e++)
        Vt[(sd+e)*64 + ((cb0^e)<<3) + jc] = vs[e];
    }
    asm volatile("s_waitcnt vmcnt(0)" ::: "memory");
    __syncthreads();
    // ---- S = Q K^T (Q pre-scaled by 0.125) ----
    f4 s[4];
    __builtin_amdgcn_s_setprio(1);
    #pragma unroll
    for (int cb=0;cb<4;cb++) {
      const int krow = cb*16+lr;
      const char* kr = ldsK + krow*128;
      bh8 kf0 = *reinterpret_cast<const bh8*>(kr + ((g  )^(lr&7))*16);
      bh8 kf1 = *reinterpret_cast<const bh8*>(kr + ((g+4)^(lr&7))*16);
      f4 z = f4{0.f,0.f,0.f,0.f};
      z = MFMA16(qf0, kf0, z);
      z = MFMA16(qf1, kf1, z);
      s[cb] = z;
    }
    __builtin_amdgcn_s_setprio(0);
    // ---- online softmax (wave-parallel, 16-lane row groups) ----
    float mx[4];
    #pragma unroll
    for (int r=0;r<4;r++) mx[r] = fmaxf(fmaxf(s[0][r],s[1][r]), fmaxf(s[2][r],s[3][r]));
    #pragma unroll
    for (int mk=1; mk<16; mk<<=1)
      #pragma unroll
      for (int r=0;r<4;r++) mx[r] = fmaxf(mx[r], __shfl_xor(mx[r], mk));
    float rs[4];
    #pragma unroll
    for (int r=0;r<4;r++) {
      const float mn = fmaxf(m_run[r], mx[r]);
      const float al = __expf(m_run[r]-mn);
      m_run[r] = mn;
      l_run[r] *= al;
      float sum = 0.f;
      #pragma unroll
      for (int cb=0;cb<4;cb++) {
        const float pv = __expf(s[cb][r]-mn);
        sum += pv;
        Pw[((l>>4)*4 + r)*72 + cb*16 + lr] = f2bf(pv);
      }
      rs[r] = sum;
      #pragma unroll
      for (int cb=0;cb<4;cb++) o[cb][r] *= al;
    }
    #pragma unroll
    for (int mk=1; mk<16; mk<<=1)
      #pragma unroll
      for (int r=0;r<4;r++) rs[r] += __shfl_xor(rs[r], mk);
    #pragma unroll
    for (int r=0;r<4;r++) l_run[r] += rs[r];
    // fence P write->read (wave-local)
    asm volatile("s_waitcnt lgkmcnt(0)" ::: "memory");
    __builtin_amdgcn_sched_barrier(0);
    bh8 pa0 = *reinterpret_cast<const bh8*>(&Pw[lr*72 + lk]);
    bh8 pa1 = *reinterpret_cast<const bh8*>(&Pw[lr*72 + 32 + lk]);
    // ---- PV: B-frags from swizzled Vt ----
    #pragma unroll
    for (int kk=0; kk<2; kk++) {
      const bh8 pa = kk ? pa1 : pa0;
      __builtin_amdgcn_s_setprio(1);
      #pragma unroll
      for (int db=0; db<4; db++) {
        const int dd = db*16 + lr;
        const int ch = (kk*4 + g) ^ (dd&7) ^ ((dd>>3)&7);
        bh8 vf = *reinterpret_cast<const bh8*>(&Vt[dd*64 + ch*8]);
        o[db] = MFMA16(pa, vf, o[db]);
      }
      __builtin_amdgcn_s_setprio(0);
    }
  }
  const int bb = bh>>4, hh = bh&15;
  #pragma unroll
  for (int db=0; db<4; db++)
    #pragma unroll
    for (int r=0;r<4;r++) {
      const int n = qrow + (l>>4)*4 + r;
      const int d = db*16 + lr;
      const float v = o[db][r] / l_run[r];
      interOut[base + (long)n*DH_ + d] = v;
      attnB[(long)(bb*N_ + n)*1024 + hh*DH_ + d] = f2bf(v);
    }
}

// ---------------- a * gelu(gate), bf16 ----------------
__global__ __launch_bounds__(256) void gelu_mul(const short* __restrict__ h, short* __restrict__ g)
{
  const long i = ((long)blockIdx.x*256 + threadIdx.x)*8;
  const long m = i >> 12;
  const int j = (int)(i & 4095);
  bh8 av = *reinterpret_cast<const bh8*>(&h[m*8192 + j]);
  bh8 gv = *reinterpret_cast<const bh8*>(&h[m*8192 + 4096 + j]);
  bh8 ov;
  #pragma unroll
  for (int e=0;e<8;e++) {
    const float a  = bf2f(av[e]);
    const float xg = bf2f(gv[e]);
    const float ge = 0.5f*xg*(1.f + erff(xg*0.70710678118f));
    ov[e] = f2bf(a*ge);
  }
  *reinterpret_cast<bh8*>(&g[i]) = ov;
}

extern "C" void kernel_launch(void* const* d_in, const int* in_sizes, int n_in,
                              void* d_out, int out_size, void* d_ws, size_t ws_size,
                              hipStream_t stream)
{
  const float* x    = (const float*)d_in[0];
  const float* Wq   = (const float*)d_in[1];
  const float* Wk   = (const float*)d_in[2];
  const float* Wv   = (const float*)d_in[3];
  const float* Wo   = (const float*)d_in[4];
  const float* bo   = (const float*)d_in[5];
  const float* ln1g = (const float*)d_in[6];
  const float* ln1b = (const float*)d_in[7];
  const float* ln3g = (const float*)d_in[8];
  const float* ln3b = (const float*)d_in[9];
  const float* Wff1 = (const float*)d_in[10];
  const float* bff1 = (const float*)d_in[11];
  const float* Wff2 = (const float*)d_in[12];
  const float* bff2 = (const float*)d_in[13];
  float* out = (float*)d_out;
  const long SZ = (long)M_*D_;
  float* out_x     = out;
  float* out_q     = out + SZ;
  float* out_k     = out + 2*SZ;
  float* out_v     = out + 3*SZ;
  float* out_inter = out + 4*SZ;
  float* out_xf    = out + 5*SZ;

  char* p = (char*)d_ws;
  auto alloc = [&](size_t bytes){ void* r = (void*)p; p += (bytes + 255) & ~(size_t)255; return r; };
  short* xf_bf  = (short*)alloc(SZ*2);
  short* q_bf   = (short*)alloc(SZ*2);
  short* k_bf   = (short*)alloc(SZ*2);
  short* v_bf   = (short*)alloc(SZ*2);
  short* at_bf  = (short*)alloc(SZ*2);
  float* x2     = (float*)alloc(SZ*4);
  short* x2n_bf = (short*)alloc(SZ*2);
  short* h_bf   = (short*)alloc((size_t)M_*8192*2);
  short* g_bf   = (short*)alloc((size_t)M_*4096*2);
  short* WqT    = (short*)alloc((size_t)1024*1024*2);
  short* WkT    = (short*)alloc((size_t)1024*1024*2);
  short* WvT    = (short*)alloc((size_t)1024*1024*2);
  short* WoT    = (short*)alloc((size_t)1024*1024*2);
  short* Wff1T  = (short*)alloc((size_t)8192*1024*2);
  short* Wff2T  = (short*)alloc((size_t)1024*4096*2);
  (void)in_sizes; (void)n_in; (void)out_size; (void)ws_size;

  dim3 blk(256);
  transpose_cast<<<dim3(32,32),  blk, 0, stream>>>(Wq,   WqT,   1024, 1024);
  transpose_cast<<<dim3(32,32),  blk, 0, stream>>>(Wk,   WkT,   1024, 1024);
  transpose_cast<<<dim3(32,32),  blk, 0, stream>>>(Wv,   WvT,   1024, 1024);
  transpose_cast<<<dim3(32,32),  blk, 0, stream>>>(Wo,   WoT,   1024, 1024);
  transpose_cast<<<dim3(256,32), blk, 0, stream>>>(Wff1, Wff1T, 1024, 8192);
  transpose_cast<<<dim3(32,128), blk, 0, stream>>>(Wff2, Wff2T, 4096, 1024);
  ln_kernel<<<M_, blk, 0, stream>>>(x, ln1g, ln1b, out_xf, xf_bf);
  gemm_qkv<<<dim3(32,24), blk, 0, stream>>>(xf_bf, WqT, WkT, WvT,
                                            out_q, out_k, out_v, q_bf, k_bf, v_bf);
  attn_kernel<<<dim3(32,32), blk, 0, stream>>>(q_bf, k_bf, v_bf, out_inter, at_bf);
  gemm_bt<1><<<dim3(32,8),  blk, 0, stream>>>(at_bf,  WoT,   1024, 1024, bo,   x,   x2,    nullptr);
  ln_kernel<<<M_, blk, 0, stream>>>(x2, ln3g, ln3b, nullptr, x2n_bf);
  gemm_bt<2><<<dim3(32,64), blk, 0, stream>>>(x2n_bf, Wff1T, 8192, 1024, bff1, nullptr, nullptr, h_bf);
  gelu_mul<<<8192, blk, 0, stream>>>(h_bf, g_bf);
  gemm_bt<1><<<dim3(32,8),  blk, 0, stream>>>(g_bf,   Wff2T, 1024, 4096, bff2, x2,  out_x, nullptr);
}

// Round 4
// 604.999 us; speedup vs baseline: 1.0852x; 1.0108x over previous
//
#include <hip/hip_runtime.h>
#include <hip/hip_bf16.h>

#define B_ 2
#define N_ 2048
#define D_ 1024
#define H_ 16
#define DH_ 64
#define M_ 4096
#define FFI_ 4096

typedef __attribute__((ext_vector_type(8))) short bh8;
typedef __attribute__((ext_vector_type(4))) float f4;

#define DEV static __device__ __forceinline__

DEV short f2bf(float f) { __hip_bfloat16 h = __float2bfloat16(f); return *reinterpret_cast<short*>(&h); }
DEV float bf2f(short s) { __hip_bfloat16 h = *reinterpret_cast<__hip_bfloat16*>(&s); return __bfloat162float(h); }

#define GLDS(gp, lp) __builtin_amdgcn_global_load_lds((const __attribute__((address_space(1))) void*)(gp), (__attribute__((address_space(3))) void*)(lp), 16, 0, 0)
#define MFMA16(a,b,c) __builtin_amdgcn_mfma_f32_16x16x32_bf16(a,b,c,0,0,0)

// ---------------- LayerNorm: fp32 in -> fp32 out (optional) + bf16 out ----------------
__global__ __launch_bounds__(256) void ln_kernel(const float* __restrict__ x,
    const float* __restrict__ g, const float* __restrict__ b,
    float* __restrict__ outF, short* __restrict__ outB)
{
  const int row = blockIdx.x;
  const int t = threadIdx.x;
  const float4 v = reinterpret_cast<const float4*>(x + (long)row*D_)[t];
  float s = v.x+v.y+v.z+v.w;
  float sq = v.x*v.x+v.y*v.y+v.z*v.z+v.w*v.w;
  #pragma unroll
  for (int o=32;o>0;o>>=1){ s += __shfl_xor(s,o); sq += __shfl_xor(sq,o); }
  __shared__ float red[8];
  const int w = t>>6, l = t&63;
  if (l==0){ red[w]=s; red[4+w]=sq; }
  __syncthreads();
  s  = red[0]+red[1]+red[2]+red[3];
  sq = red[4]+red[5]+red[6]+red[7];
  const float mu = s*(1.f/D_);
  const float rstd = rsqrtf(sq*(1.f/D_) - mu*mu + 1e-5f);
  const float4 gv = reinterpret_cast<const float4*>(g)[t];
  const float4 bv = reinterpret_cast<const float4*>(b)[t];
  float4 y;
  y.x=(v.x-mu)*rstd*gv.x+bv.x; y.y=(v.y-mu)*rstd*gv.y+bv.y;
  y.z=(v.z-mu)*rstd*gv.z+bv.z; y.w=(v.w-mu)*rstd*gv.w+bv.w;
  if (outF) reinterpret_cast<float4*>(outF + (long)row*D_)[t] = y;
  short4 ys; ys.x=f2bf(y.x); ys.y=f2bf(y.y); ys.z=f2bf(y.z); ys.w=f2bf(y.w);
  reinterpret_cast<short4*>(outB + (long)row*D_)[t] = ys;
}

// ---------------- transpose + fp32->bf16 cast: in R x C -> out C x R ----------------
__global__ __launch_bounds__(256) void transpose_cast(const float* __restrict__ in,
    short* __restrict__ out, int R, int C)
{
  __shared__ float tile[32][33];
  const int tx = threadIdx.x & 31, ty = threadIdx.x >> 5;
  const int c0 = blockIdx.x*32, r0 = blockIdx.y*32;
  #pragma unroll
  for (int i=0;i<4;i++) tile[ty+i*8][tx] = in[(long)(r0+ty+i*8)*C + c0+tx];
  __syncthreads();
  #pragma unroll
  for (int i=0;i<4;i++) out[(long)(c0+ty+i*8)*R + r0+tx] = f2bf(tile[tx][ty+i*8]);
}

// 4 square 1024x1024 weights in one launch (z selects)
__global__ __launch_bounds__(256) void transpose_cast4(
    const float* __restrict__ i0, const float* __restrict__ i1,
    const float* __restrict__ i2, const float* __restrict__ i3,
    short* __restrict__ o0, short* __restrict__ o1,
    short* __restrict__ o2, short* __restrict__ o3)
{
  const int z = blockIdx.z;
  const float* in = z==0?i0 : z==1?i1 : z==2?i2 : i3;
  short* out      = z==0?o0 : z==1?o1 : z==2?o2 : o3;
  __shared__ float tile[32][33];
  const int tx = threadIdx.x & 31, ty = threadIdx.x >> 5;
  const int c0 = blockIdx.x*32, r0 = blockIdx.y*32;
  #pragma unroll
  for (int i=0;i<4;i++) tile[ty+i*8][tx] = in[(long)(r0+ty+i*8)*1024 + c0+tx];
  __syncthreads();
  #pragma unroll
  for (int i=0;i<4;i++) out[(long)(c0+ty+i*8)*1024 + r0+tx] = f2bf(tile[tx][ty+i*8]);
}

// ---------------- GEMM core: C(BMx128) = A(MxK) * BT(NxK)^T, bf16 MFMA ----------------
// BM=128: 4 waves in 2x2, each 64x64, acc[4][4].  BM=64: each wave 32x64, acc[2][4].
template<int BM>
DEV void gemm_core(const short* __restrict__ A, const short* __restrict__ BT, int K,
                   int m0, int n0, short* lA, short* lB, f4 (&acc)[BM/32][4])
{
  const int t = threadIdx.x, w = t>>6, l = t&63;
  const int wrow = (w>>1)*(BM/2), wcol = (w&1)*64;
  const int lr = l&15, lk = (l>>4)*8;
  const int sr = t>>2, sc = (t&3)*8;
  const short* gA = A  + (long)(m0+sr)*K + sc;
  const short* gB = BT + (long)(n0+sr)*K + sc;
  #pragma unroll
  for (int i=0;i<BM/32;i++)
    #pragma unroll
    for (int j=0;j<4;j++) acc[i][j] = f4{0.f,0.f,0.f,0.f};
  for (int k0=0; k0<K; k0+=32) {
    __syncthreads();
    #pragma unroll
    for (int i=0;i<BM/64;i++)
      GLDS(gA + (long)i*64*K, &lA[i*2048 + w*512]);
    GLDS(gB,              &lB[w*512]);
    GLDS(gB + (long)64*K, &lB[2048 + w*512]);
    gA += 32; gB += 32;
    asm volatile("s_waitcnt vmcnt(0)" ::: "memory");
    __syncthreads();
    bh8 af[BM/32], bf_[4];
    #pragma unroll
    for (int i=0;i<BM/32;i++) af[i] = *reinterpret_cast<const bh8*>(&lA[(wrow+i*16+lr)*32 + lk]);
    #pragma unroll
    for (int j=0;j<4;j++) bf_[j] = *reinterpret_cast<const bh8*>(&lB[(wcol+j*16+lr)*32 + lk]);
    #pragma unroll
    for (int i=0;i<BM/32;i++)
      #pragma unroll
      for (int j=0;j<4;j++)
        acc[i][j] = MFMA16(af[i], bf_[j], acc[i][j]);
  }
}

// ---------------- fused QKV GEMM: writes fp32 (B*H,N,DH) outputs + bf16 ws copies ----------------
__global__ __launch_bounds__(256) void gemm_qkv(const short* __restrict__ A,
    const short* __restrict__ BTq, const short* __restrict__ BTk, const short* __restrict__ BTv,
    float* __restrict__ oQ, float* __restrict__ oK, float* __restrict__ oV,
    short* __restrict__ bQ, short* __restrict__ bK, short* __restrict__ bV)
{
  __shared__ short lA[4096], lB[4096];
  const int m0 = blockIdx.x*128;
  const int by = blockIdx.y, sel = by>>3, n0 = (by&7)*128;
  const short* BT = sel==0 ? BTq : (sel==1 ? BTk : BTv);
  float* oF = sel==0 ? oQ : (sel==1 ? oK : oV);
  short* oB = sel==0 ? bQ : (sel==1 ? bK : bV);
  const float bscale = sel==0 ? 0.125f : 1.0f;   // pre-scale Q by DH^-0.5 (exact pow2)
  f4 acc[4][4];
  gemm_core<128>(A, BT, 1024, m0, n0, lA, lB, acc);
  const int t = threadIdx.x, w = t>>6, l = t&63;
  const int wrow=(w>>1)*64, wcol=(w&1)*64, lr=l&15;
  #pragma unroll
  for (int i=0;i<4;i++)
    #pragma unroll
    for (int j=0;j<4;j++)
      #pragma unroll
      for (int r=0;r<4;r++) {
        const int grow = m0 + wrow + i*16 + (l>>4)*4 + r;
        const int gcol = n0 + wcol + j*16 + lr;
        const int bb = grow >> 11, nn = grow & 2047;
        const int hh = gcol >> 6, dd = gcol & 63;
        const long oi = ((long)(bb*H_ + hh)*N_ + nn)*DH_ + dd;
        const float v = acc[i][j][r];
        oF[oi] = v;
        oB[oi] = f2bf(v * bscale);
      }
}

// ---------------- generic GEMM epilogues: 1 = +bias+resid -> f32, 2 = +bias -> bf16 ----------------
template<int MODE, int BM>
__global__ __launch_bounds__(256) void gemm_bt(const short* __restrict__ A,
    const short* __restrict__ BT, int Ndim, int K,
    const float* __restrict__ bias, const float* __restrict__ resid,
    float* __restrict__ outF, short* __restrict__ outB)
{
  __shared__ short lA[BM*32], lB[4096];
  const int m0 = blockIdx.x*BM, n0 = blockIdx.y*128;
  f4 acc[BM/32][4];
  gemm_core<BM>(A, BT, K, m0, n0, lA, lB, acc);
  const int t = threadIdx.x, w=t>>6, l=t&63;
  const int wrow=(w>>1)*(BM/2), wcol=(w&1)*64, lr=l&15;
  #pragma unroll
  for (int i=0;i<BM/32;i++)
    #pragma unroll
    for (int j=0;j<4;j++)
      #pragma unroll
      for (int r=0;r<4;r++) {
        const int grow = m0 + wrow + i*16 + (l>>4)*4 + r;
        const int gcol = n0 + wcol + j*16 + lr;
        const long oi = (long)grow*Ndim + gcol;
        const float v = acc[i][j][r] + bias[gcol];
        if (MODE==1) outF[oi] = v + resid[oi];
        else         outB[oi] = f2bf(v);
      }
}

// ---------------- flash attention (2-phase pipelined staging) ----------------
// K staged via global_load_lds, both-sides XOR chunk swizzle (rule #21).
// V staged transposed by reg-staging with two-level chunk swizzle.
// Double-buffered LDS; next tile's K GLDS + V global loads issued BEFORE
// computing current tile; raw s_barrier + explicit waits (no vmcnt(0) drain
// of in-flight prefetch by __syncthreads).
__global__ __launch_bounds__(256) void attn_kernel(const short* __restrict__ Q,
    const short* __restrict__ Kb, const short* __restrict__ Vb,
    float* __restrict__ interOut, short* __restrict__ attnB)
{
  __shared__ short Kt[2*64*64];   // 16 KiB, dbuf
  __shared__ short Vt[2*64*64];   // 16 KiB, dbuf, V^T [d][j] swizzled
  __shared__ short Pt[4*16*72];   // per-wave P tiles, padded
  const int t = threadIdx.x, w = t>>6, l = t&63;
  // XCD-aware swizzle: contiguous 128-block chunk (4 heads) per XCD
  const int bid = blockIdx.x;
  const int nb = (bid & 7)*128 + (bid >> 3);
  const int bh = nb >> 5;
  const int q0 = (nb & 31)*64;
  const int lr = l&15, lk = (l>>4)*8, g = l>>4;
  const long base = (long)bh * (N_*DH_);
  const int qrow = q0 + w*16;
  bh8 qf0 = *reinterpret_cast<const bh8*>(&Q[base + (long)(qrow+lr)*DH_ + lk]);
  bh8 qf1 = *reinterpret_cast<const bh8*>(&Q[base + (long)(qrow+lr)*DH_ + 32 + lk]);
  f4 o[4];
  #pragma unroll
  for (int i=0;i<4;i++) o[i]=f4{0.f,0.f,0.f,0.f};
  float m_run[4], l_run[4];
  #pragma unroll
  for (int r=0;r<4;r++){ m_run[r]=-1e30f; l_run[r]=0.f; }
  short* Pw = &Pt[w*16*72];
  const char* ldsK = (const char*)Kt;
  const int beta0 = w*2048 + l*16;                 // K staging byte slot
  const int srow = t>>3, sdp = t&7, sd = sdp*8;    // V staging coords
  const int NT = N_/64;
  int4 vv[2];
  // ---- prologue: issue tile-0 K GLDS + V loads ----
  {
    const char* Kg = (const char*)(Kb + base);
    #pragma unroll
    for (int i=0;i<2;i++) {
      const int beta = beta0 + i*1024;
      const int krow = beta>>7, kpch = (beta>>4)&7;
      GLDS(Kg + krow*128 + (kpch ^ (krow&7))*16, (char*)Kt + (w*2+i)*1024);
    }
    #pragma unroll
    for (int it=0; it<2; it++)
      vv[it] = *reinterpret_cast<const int4*>(&Vb[base + (long)(it*32+srow)*DH_ + sd]);
  }
  for (int kt=0; kt<NT; kt++) {
    const int b = kt & 1;
    asm volatile("s_waitcnt vmcnt(0)" ::: "memory");  // tile-kt K in LDS, V in regs
    // ---- write V regs -> Vt[b] (swizzled scalar writes) ----
    #pragma unroll
    for (int it=0; it<2; it++) {
      const short* vs = reinterpret_cast<const short*>(&vv[it]);
      const int cb0 = (it*4 + (srow>>3)) ^ sdp;   // (j>>3) ^ sdp
      const int jc  = srow & 7;
      #pragma unroll
      for (int e=0;e<8;e++)
        Vt[b*4096 + (sd+e)*64 + ((cb0^e)<<3) + jc] = vs[e];
    }
    // ---- issue next tile's K GLDS + V loads (prefetch across compute) ----
    if (kt+1 < NT) {
      const char* Kg = (const char*)(Kb + base + (long)(kt+1)*64*DH_);
      #pragma unroll
      for (int i=0;i<2;i++) {
        const int beta = beta0 + i*1024;
        const int krow = beta>>7, kpch = (beta>>4)&7;
        GLDS(Kg + krow*128 + (kpch ^ (krow&7))*16, (char*)Kt + (b^1)*8192 + (w*2+i)*1024);
      }
      #pragma unroll
      for (int it=0; it<2; it++)
        vv[it] = *reinterpret_cast<const int4*>(&Vb[base + (long)((kt+1)*64 + it*32+srow)*DH_ + sd]);
    }
    asm volatile("s_waitcnt lgkmcnt(0)" ::: "memory"); // V writes landed
    __builtin_amdgcn_s_barrier();                      // buf b fully staged
    // ---- S = Q K^T (Q pre-scaled by 0.125) ----
    f4 s[4];
    __builtin_amdgcn_s_setprio(1);
    #pragma unroll
    for (int cb=0;cb<4;cb++) {
      const int krow = cb*16+lr;
      const char* kr = ldsK + b*8192 + krow*128;
      bh8 kf0 = *reinterpret_cast<const bh8*>(kr + ((g  )^(lr&7))*16);
      bh8 kf1 = *reinterpret_cast<const bh8*>(kr + ((g+4)^(lr&7))*16);
      f4 z = f4{0.f,0.f,0.f,0.f};
      z = MFMA16(qf0, kf0, z);
      z = MFMA16(qf1, kf1, z);
      s[cb] = z;
    }
    __builtin_amdgcn_s_setprio(0);
    // ---- online softmax (wave-parallel, 16-lane row groups) ----
    float mx[4];
    #pragma unroll
    for (int r=0;r<4;r++) mx[r] = fmaxf(fmaxf(s[0][r],s[1][r]), fmaxf(s[2][r],s[3][r]));
    #pragma unroll
    for (int mk=1; mk<16; mk<<=1)
      #pragma unroll
      for (int r=0;r<4;r++) mx[r] = fmaxf(mx[r], __shfl_xor(mx[r], mk));
    float rs[4];
    #pragma unroll
    for (int r=0;r<4;r++) {
      const float mn = fmaxf(m_run[r], mx[r]);
      const float al = __expf(m_run[r]-mn);
      m_run[r] = mn;
      l_run[r] *= al;
      float sum = 0.f;
      #pragma unroll
      for (int cb=0;cb<4;cb++) {
        const float pv = __expf(s[cb][r]-mn);
        sum += pv;
        Pw[((l>>4)*4 + r)*72 + cb*16 + lr] = f2bf(pv);
      }
      rs[r] = sum;
      #pragma unroll
      for (int cb=0;cb<4;cb++) o[cb][r] *= al;
    }
    #pragma unroll
    for (int mk=1; mk<16; mk<<=1)
      #pragma unroll
      for (int r=0;r<4;r++) rs[r] += __shfl_xor(rs[r], mk);
    #pragma unroll
    for (int r=0;r<4;r++) l_run[r] += rs[r];
    // fence P write->read (wave-local)
    asm volatile("s_waitcnt lgkmcnt(0)" ::: "memory");
    __builtin_amdgcn_sched_barrier(0);
    bh8 pa0 = *reinterpret_cast<const bh8*>(&Pw[lr*72 + lk]);
    bh8 pa1 = *reinterpret_cast<const bh8*>(&Pw[lr*72 + 32 + lk]);
    // ---- PV: B-frags from swizzled Vt[b] ----
    #pragma unroll
    for (int kk=0; kk<2; kk++) {
      const bh8 pa = kk ? pa1 : pa0;
      __builtin_amdgcn_s_setprio(1);
      #pragma unroll
      for (int db=0; db<4; db++) {
        const int dd = db*16 + lr;
        const int ch = (kk*4 + g) ^ (dd&7) ^ ((dd>>3)&7);
        bh8 vf = *reinterpret_cast<const bh8*>(&Vt[b*4096 + dd*64 + ch*8]);
        o[db] = MFMA16(pa, vf, o[db]);
      }
      __builtin_amdgcn_s_setprio(0);
    }
    __builtin_amdgcn_s_barrier();   // all waves done reading buf b
  }
  const int bb = bh>>4, hh = bh&15;
  #pragma unroll
  for (int db=0; db<4; db++)
    #pragma unroll
    for (int r=0;r<4;r++) {
      const int n = qrow + (l>>4)*4 + r;
      const int d = db*16 + lr;
      const float v = o[db][r] / l_run[r];
      interOut[base + (long)n*DH_ + d] = v;
      attnB[(long)(bb*N_ + n)*1024 + hh*DH_ + d] = f2bf(v);
    }
}

// ---------------- a * gelu(gate), bf16 ----------------
__global__ __launch_bounds__(256) void gelu_mul(const short* __restrict__ h, short* __restrict__ g)
{
  const long i = ((long)blockIdx.x*256 + threadIdx.x)*8;
  const long m = i >> 12;
  const int j = (int)(i & 4095);
  bh8 av = *reinterpret_cast<const bh8*>(&h[m*8192 + j]);
  bh8 gv = *reinterpret_cast<const bh8*>(&h[m*8192 + 4096 + j]);
  bh8 ov;
  #pragma unroll
  for (int e=0;e<8;e++) {
    const float a  = bf2f(av[e]);
    const float xg = bf2f(gv[e]);
    const float ge = 0.5f*xg*(1.f + erff(xg*0.70710678118f));
    ov[e] = f2bf(a*ge);
  }
  *reinterpret_cast<bh8*>(&g[i]) = ov;
}

extern "C" void kernel_launch(void* const* d_in, const int* in_sizes, int n_in,
                              void* d_out, int out_size, void* d_ws, size_t ws_size,
                              hipStream_t stream)
{
  const float* x    = (const float*)d_in[0];
  const float* Wq   = (const float*)d_in[1];
  const float* Wk   = (const float*)d_in[2];
  const float* Wv   = (const float*)d_in[3];
  const float* Wo   = (const float*)d_in[4];
  const float* bo   = (const float*)d_in[5];
  const float* ln1g = (const float*)d_in[6];
  const float* ln1b = (const float*)d_in[7];
  const float* ln3g = (const float*)d_in[8];
  const float* ln3b = (const float*)d_in[9];
  const float* Wff1 = (const float*)d_in[10];
  const float* bff1 = (const float*)d_in[11];
  const float* Wff2 = (const float*)d_in[12];
  const float* bff2 = (const float*)d_in[13];
  float* out = (float*)d_out;
  const long SZ = (long)M_*D_;
  float* out_x     = out;
  float* out_q     = out + SZ;
  float* out_k     = out + 2*SZ;
  float* out_v     = out + 3*SZ;
  float* out_inter = out + 4*SZ;
  float* out_xf    = out + 5*SZ;

  char* p = (char*)d_ws;
  auto alloc = [&](size_t bytes){ void* r = (void*)p; p += (bytes + 255) & ~(size_t)255; return r; };
  short* xf_bf  = (short*)alloc(SZ*2);
  short* q_bf   = (short*)alloc(SZ*2);
  short* k_bf   = (short*)alloc(SZ*2);
  short* v_bf   = (short*)alloc(SZ*2);
  short* at_bf  = (short*)alloc(SZ*2);
  float* x2     = (float*)alloc(SZ*4);
  short* x2n_bf = (short*)alloc(SZ*2);
  short* h_bf   = (short*)alloc((size_t)M_*8192*2);
  short* g_bf   = (short*)alloc((size_t)M_*4096*2);
  short* WqT    = (short*)alloc((size_t)1024*1024*2);
  short* WkT    = (short*)alloc((size_t)1024*1024*2);
  short* WvT    = (short*)alloc((size_t)1024*1024*2);
  short* WoT    = (short*)alloc((size_t)1024*1024*2);
  short* Wff1T  = (short*)alloc((size_t)8192*1024*2);
  short* Wff2T  = (short*)alloc((size_t)1024*4096*2);
  (void)in_sizes; (void)n_in; (void)out_size; (void)ws_size;

  dim3 blk(256);
  transpose_cast4<<<dim3(32,32,4), blk, 0, stream>>>(Wq, Wk, Wv, Wo, WqT, WkT, WvT, WoT);
  transpose_cast<<<dim3(256,32), blk, 0, stream>>>(Wff1, Wff1T, 1024, 8192);
  transpose_cast<<<dim3(32,128), blk, 0, stream>>>(Wff2, Wff2T, 4096, 1024);
  ln_kernel<<<M_, blk, 0, stream>>>(x, ln1g, ln1b, out_xf, xf_bf);
  gemm_qkv<<<dim3(32,24), blk, 0, stream>>>(xf_bf, WqT, WkT, WvT,
                                            out_q, out_k, out_v, q_bf, k_bf, v_bf);
  attn_kernel<<<1024, blk, 0, stream>>>(q_bf, k_bf, v_bf, out_inter, at_bf);
  gemm_bt<1,64><<<dim3(64,8),  blk, 0, stream>>>(at_bf,  WoT,   1024, 1024, bo,   x,   x2,    nullptr);
  ln_kernel<<<M_, blk, 0, stream>>>(x2, ln3g, ln3b, nullptr, x2n_bf);
  gemm_bt<2,128><<<dim3(32,64), blk, 0, stream>>>(x2n_bf, Wff1T, 8192, 1024, bff1, nullptr, nullptr, h_bf);
  gelu_mul<<<8192, blk, 0, stream>>>(h_bf, g_bf);
  gemm_bt<1,64><<<dim3(64,8),  blk, 0, stream>>>(g_bf,   Wff2T, 1024, 4096, bff2, x2,  out_x, nullptr);
}

// Round 5
// 577.283 us; speedup vs baseline: 1.1373x; 1.0480x over previous
//
#include <hip/hip_runtime.h>
#include <hip/hip_bf16.h>

#define B_ 2
#define N_ 2048
#define D_ 1024
#define H_ 16
#define DH_ 64
#define M_ 4096
#define FFI_ 4096

typedef __attribute__((ext_vector_type(8))) short bh8;
typedef __attribute__((ext_vector_type(4))) float f4;

#define DEV static __device__ __forceinline__

DEV short f2bf(float f) { __hip_bfloat16 h = __float2bfloat16(f); return *reinterpret_cast<short*>(&h); }
DEV float bf2f(short s) { __hip_bfloat16 h = *reinterpret_cast<__hip_bfloat16*>(&s); return __bfloat162float(h); }
DEV int   f2bits(float f){ int i; __builtin_memcpy(&i,&f,4); return i; }
DEV float bits2f(int i){ float f; __builtin_memcpy(&f,&i,4); return f; }

// butterfly reduce over each aligned 16-lane group, pure VALU (no LDS)
DEV float dpp_max16(float x) {
  x = fmaxf(x, bits2f(__builtin_amdgcn_update_dpp(f2bits(x), f2bits(x), 0xB1, 0xF, 0xF, true)));  // quad_perm xor1
  x = fmaxf(x, bits2f(__builtin_amdgcn_update_dpp(f2bits(x), f2bits(x), 0x4E, 0xF, 0xF, true)));  // quad_perm xor2
  x = fmaxf(x, bits2f(__builtin_amdgcn_update_dpp(f2bits(x), f2bits(x), 0x141,0xF, 0xF, true)));  // row_half_mirror
  x = fmaxf(x, bits2f(__builtin_amdgcn_update_dpp(f2bits(x), f2bits(x), 0x140,0xF, 0xF, true)));  // row_mirror
  return x;
}
DEV float dpp_sum16(float x) {
  x += bits2f(__builtin_amdgcn_update_dpp(f2bits(x), f2bits(x), 0xB1, 0xF, 0xF, true));
  x += bits2f(__builtin_amdgcn_update_dpp(f2bits(x), f2bits(x), 0x4E, 0xF, 0xF, true));
  x += bits2f(__builtin_amdgcn_update_dpp(f2bits(x), f2bits(x), 0x141,0xF, 0xF, true));
  x += bits2f(__builtin_amdgcn_update_dpp(f2bits(x), f2bits(x), 0x140,0xF, 0xF, true));
  return x;
}

#define GLDS(gp, lp) __builtin_amdgcn_global_load_lds((const __attribute__((address_space(1))) void*)(gp), (__attribute__((address_space(3))) void*)(lp), 16, 0, 0)
#define MFMA16(a,b,c) __builtin_amdgcn_mfma_f32_16x16x32_bf16(a,b,c,0,0,0)

// ---------------- LayerNorm: fp32 in -> fp32 out (optional) + bf16 out ----------------
__global__ __launch_bounds__(256) void ln_kernel(const float* __restrict__ x,
    const float* __restrict__ g, const float* __restrict__ b,
    float* __restrict__ outF, short* __restrict__ outB)
{
  const int row = blockIdx.x;
  const int t = threadIdx.x;
  const float4 v = reinterpret_cast<const float4*>(x + (long)row*D_)[t];
  float s = v.x+v.y+v.z+v.w;
  float sq = v.x*v.x+v.y*v.y+v.z*v.z+v.w*v.w;
  #pragma unroll
  for (int o=32;o>0;o>>=1){ s += __shfl_xor(s,o); sq += __shfl_xor(sq,o); }
  __shared__ float red[8];
  const int w = t>>6, l = t&63;
  if (l==0){ red[w]=s; red[4+w]=sq; }
  __syncthreads();
  s  = red[0]+red[1]+red[2]+red[3];
  sq = red[4]+red[5]+red[6]+red[7];
  const float mu = s*(1.f/D_);
  const float rstd = rsqrtf(sq*(1.f/D_) - mu*mu + 1e-5f);
  const float4 gv = reinterpret_cast<const float4*>(g)[t];
  const float4 bv = reinterpret_cast<const float4*>(b)[t];
  float4 y;
  y.x=(v.x-mu)*rstd*gv.x+bv.x; y.y=(v.y-mu)*rstd*gv.y+bv.y;
  y.z=(v.z-mu)*rstd*gv.z+bv.z; y.w=(v.w-mu)*rstd*gv.w+bv.w;
  if (outF) reinterpret_cast<float4*>(outF + (long)row*D_)[t] = y;
  short4 ys; ys.x=f2bf(y.x); ys.y=f2bf(y.y); ys.z=f2bf(y.z); ys.w=f2bf(y.w);
  reinterpret_cast<short4*>(outB + (long)row*D_)[t] = ys;
}

// ---------------- transpose + fp32->bf16 cast: in R x C -> out C x R ----------------
__global__ __launch_bounds__(256) void transpose_cast(const float* __restrict__ in,
    short* __restrict__ out, int R, int C)
{
  __shared__ float tile[32][33];
  const int tx = threadIdx.x & 31, ty = threadIdx.x >> 5;
  const int c0 = blockIdx.x*32, r0 = blockIdx.y*32;
  #pragma unroll
  for (int i=0;i<4;i++) tile[ty+i*8][tx] = in[(long)(r0+ty+i*8)*C + c0+tx];
  __syncthreads();
  #pragma unroll
  for (int i=0;i<4;i++) out[(long)(c0+ty+i*8)*R + r0+tx] = f2bf(tile[tx][ty+i*8]);
}

// 4 square 1024x1024 weights in one launch (z selects)
__global__ __launch_bounds__(256) void transpose_cast4(
    const float* __restrict__ i0, const float* __restrict__ i1,
    const float* __restrict__ i2, const float* __restrict__ i3,
    short* __restrict__ o0, short* __restrict__ o1,
    short* __restrict__ o2, short* __restrict__ o3)
{
  const int z = blockIdx.z;
  const float* in = z==0?i0 : z==1?i1 : z==2?i2 : i3;
  short* out      = z==0?o0 : z==1?o1 : z==2?o2 : o3;
  __shared__ float tile[32][33];
  const int tx = threadIdx.x & 31, ty = threadIdx.x >> 5;
  const int c0 = blockIdx.x*32, r0 = blockIdx.y*32;
  #pragma unroll
  for (int i=0;i<4;i++) tile[ty+i*8][tx] = in[(long)(r0+ty+i*8)*1024 + c0+tx];
  __syncthreads();
  #pragma unroll
  for (int i=0;i<4;i++) out[(long)(c0+ty+i*8)*1024 + r0+tx] = f2bf(tile[tx][ty+i*8]);
}

// ---------------- GEMM core (2-phase dbuf): C(BMx128) = A * BT^T ----------------
// lA: 2*BM*32 shorts, lB: 2*4096 shorts.
template<int BM>
DEV void gemm_core(const short* __restrict__ A, const short* __restrict__ BT, int K,
                   int m0, int n0, short* lA, short* lB, f4 (&acc)[BM/32][4])
{
  const int t = threadIdx.x, w = t>>6, l = t&63;
  const int wrow = (w>>1)*(BM/2), wcol = (w&1)*64;
  const int lr = l&15, lk = (l>>4)*8;
  const int sr = t>>2, sc = (t&3)*8;
  const int ABUF = BM*32;
  const short* gA = A  + (long)(m0+sr)*K + sc;
  const short* gB = BT + (long)(n0+sr)*K + sc;
  #pragma unroll
  for (int i=0;i<BM/32;i++)
    #pragma unroll
    for (int j=0;j<4;j++) acc[i][j] = f4{0.f,0.f,0.f,0.f};
  // prologue: stage k=0 into buf 0
  #pragma unroll
  for (int i=0;i<BM/64;i++) GLDS(gA + (long)i*64*K, &lA[i*2048 + w*512]);
  GLDS(gB,              &lB[w*512]);
  GLDS(gB + (long)64*K, &lB[2048 + w*512]);
  asm volatile("s_waitcnt vmcnt(0)" ::: "memory");
  __builtin_amdgcn_s_barrier();
  int cur = 0;
  for (int k0=0; k0<K; k0+=32) {
    const short* pA = lA + cur*ABUF;
    const short* pB = lB + cur*4096;
    if (k0+32 < K) {          // prefetch next K-step into other buf
      const int nb = cur^1;
      #pragma unroll
      for (int i=0;i<BM/64;i++) GLDS(gA + 32 + (long)i*64*K, &lA[nb*ABUF + i*2048 + w*512]);
      GLDS(gB + 32,              &lB[nb*4096 + w*512]);
      GLDS(gB + 32 + (long)64*K, &lB[nb*4096 + 2048 + w*512]);
      gA += 32; gB += 32;
    }
    bh8 af[BM/32], bf_[4];
    #pragma unroll
    for (int i=0;i<BM/32;i++) af[i] = *reinterpret_cast<const bh8*>(&pA[(wrow+i*16+lr)*32 + lk]);
    #pragma unroll
    for (int j=0;j<4;j++) bf_[j] = *reinterpret_cast<const bh8*>(&pB[(wcol+j*16+lr)*32 + lk]);
    __builtin_amdgcn_s_setprio(1);
    #pragma unroll
    for (int i=0;i<BM/32;i++)
      #pragma unroll
      for (int j=0;j<4;j++)
        acc[i][j] = MFMA16(af[i], bf_[j], acc[i][j]);
    __builtin_amdgcn_s_setprio(0);
    asm volatile("s_waitcnt vmcnt(0)" ::: "memory");
    __builtin_amdgcn_s_barrier();
    cur ^= 1;
  }
}

// ---------------- fused QKV GEMM ----------------
__global__ __launch_bounds__(256) void gemm_qkv(const short* __restrict__ A,
    const short* __restrict__ BTq, const short* __restrict__ BTk, const short* __restrict__ BTv,
    float* __restrict__ oQ, float* __restrict__ oK, float* __restrict__ oV,
    short* __restrict__ bQ, short* __restrict__ bK, short* __restrict__ bV)
{
  __shared__ short lA[2*4096], lB[2*4096];
  const int m0 = blockIdx.x*128;
  const int by = blockIdx.y, sel = by>>3, n0 = (by&7)*128;
  const short* BT = sel==0 ? BTq : (sel==1 ? BTk : BTv);
  float* oF = sel==0 ? oQ : (sel==1 ? oK : oV);
  short* oB = sel==0 ? bQ : (sel==1 ? bK : bV);
  const float bscale = sel==0 ? 0.125f : 1.0f;   // pre-scale Q by DH^-0.5 (exact pow2)
  f4 acc[4][4];
  gemm_core<128>(A, BT, 1024, m0, n0, lA, lB, acc);
  const int t = threadIdx.x, w = t>>6, l = t&63;
  const int wrow=(w>>1)*64, wcol=(w&1)*64, lr=l&15;
  #pragma unroll
  for (int i=0;i<4;i++)
    #pragma unroll
    for (int j=0;j<4;j++)
      #pragma unroll
      for (int r=0;r<4;r++) {
        const int grow = m0 + wrow + i*16 + (l>>4)*4 + r;
        const int gcol = n0 + wcol + j*16 + lr;
        const int bb = grow >> 11, nn = grow & 2047;
        const int hh = gcol >> 6, dd = gcol & 63;
        const long oi = ((long)(bb*H_ + hh)*N_ + nn)*DH_ + dd;
        const float v = acc[i][j][r];
        oF[oi] = v;
        oB[oi] = f2bf(v * bscale);
      }
}

// ---------------- generic GEMM epilogue: +bias+resid -> f32 ----------------
template<int MODE, int BM>
__global__ __launch_bounds__(256) void gemm_bt(const short* __restrict__ A,
    const short* __restrict__ BT, int Ndim, int K,
    const float* __restrict__ bias, const float* __restrict__ resid,
    float* __restrict__ outF, short* __restrict__ outB)
{
  __shared__ short lA[2*BM*32], lB[2*4096];
  const int m0 = blockIdx.x*BM, n0 = blockIdx.y*128;
  f4 acc[BM/32][4];
  gemm_core<BM>(A, BT, K, m0, n0, lA, lB, acc);
  const int t = threadIdx.x, w=t>>6, l=t&63;
  const int wrow=(w>>1)*(BM/2), wcol=(w&1)*64, lr=l&15;
  #pragma unroll
  for (int i=0;i<BM/32;i++)
    #pragma unroll
    for (int j=0;j<4;j++)
      #pragma unroll
      for (int r=0;r<4;r++) {
        const int grow = m0 + wrow + i*16 + (l>>4)*4 + r;
        const int gcol = n0 + wcol + j*16 + lr;
        const long oi = (long)grow*Ndim + gcol;
        const float v = acc[i][j][r] + bias[gcol];
        if (MODE==1) outF[oi] = v + resid[oi];
        else         outB[oi] = f2bf(v);
      }
}

// ---------------- FF1 fused with a*gelu(gate): out bf16 4096x4096 ----------------
// Dual B-tile: cols n0..n0+127 of h ("a") and 4096+n0.. ("gate").
__global__ __launch_bounds__(256) void gemm_ff1(const short* __restrict__ A,
    const short* __restrict__ BT, const float* __restrict__ bias,
    short* __restrict__ outG)
{
  __shared__ short lA[2*2048], lB[2*4096], lC[2*4096];
  const int m0 = blockIdx.x*64, n0 = blockIdx.y*128;
  const int t = threadIdx.x, w = t>>6, l = t&63;
  const int wrow = (w>>1)*32, wcol = (w&1)*64;
  const int lr = l&15, lk = (l>>4)*8;
  const int sr = t>>2, sc = (t&3)*8;
  const int K = 1024;
  const short* gA = A  + (long)(m0+sr)*K + sc;
  const short* gB = BT + (long)(n0+sr)*K + sc;
  const short* gC = BT + (long)(4096+n0+sr)*K + sc;
  f4 aa[2][4], ag[2][4];
  #pragma unroll
  for (int i=0;i<2;i++)
    #pragma unroll
    for (int j=0;j<4;j++){ aa[i][j]=f4{0,0,0,0}; ag[i][j]=f4{0,0,0,0}; }
  GLDS(gA, &lA[w*512]);
  GLDS(gB,              &lB[w*512]);
  GLDS(gB + (long)64*K, &lB[2048 + w*512]);
  GLDS(gC,              &lC[w*512]);
  GLDS(gC + (long)64*K, &lC[2048 + w*512]);
  asm volatile("s_waitcnt vmcnt(0)" ::: "memory");
  __builtin_amdgcn_s_barrier();
  int cur = 0;
  for (int k0=0; k0<K; k0+=32) {
    const short* pA = lA + cur*2048;
    const short* pB = lB + cur*4096;
    const short* pC = lC + cur*4096;
    if (k0+32 < K) {
      const int nb = cur^1;
      GLDS(gA + 32, &lA[nb*2048 + w*512]);
      GLDS(gB + 32,              &lB[nb*4096 + w*512]);
      GLDS(gB + 32 + (long)64*K, &lB[nb*4096 + 2048 + w*512]);
      GLDS(gC + 32,              &lC[nb*4096 + w*512]);
      GLDS(gC + 32 + (long)64*K, &lC[nb*4096 + 2048 + w*512]);
      gA += 32; gB += 32; gC += 32;
    }
    bh8 af[2], bf_[4], cf[4];
    #pragma unroll
    for (int i=0;i<2;i++) af[i] = *reinterpret_cast<const bh8*>(&pA[(wrow+i*16+lr)*32 + lk]);
    #pragma unroll
    for (int j=0;j<4;j++){
      bf_[j] = *reinterpret_cast<const bh8*>(&pB[(wcol+j*16+lr)*32 + lk]);
      cf[j]  = *reinterpret_cast<const bh8*>(&pC[(wcol+j*16+lr)*32 + lk]);
    }
    __builtin_amdgcn_s_setprio(1);
    #pragma unroll
    for (int i=0;i<2;i++)
      #pragma unroll
      for (int j=0;j<4;j++){
        aa[i][j] = MFMA16(af[i], bf_[j], aa[i][j]);
        ag[i][j] = MFMA16(af[i], cf[j],  ag[i][j]);
      }
    __builtin_amdgcn_s_setprio(0);
    asm volatile("s_waitcnt vmcnt(0)" ::: "memory");
    __builtin_amdgcn_s_barrier();
    cur ^= 1;
  }
  #pragma unroll
  for (int i=0;i<2;i++)
    #pragma unroll
    for (int j=0;j<4;j++)
      #pragma unroll
      for (int r=0;r<4;r++) {
        const int grow = m0 + wrow + i*16 + (l>>4)*4 + r;
        const int gcol = n0 + wcol + j*16 + lr;
        const float va = aa[i][j][r] + bias[gcol];
        const float vg = ag[i][j][r] + bias[4096+gcol];
        const float ge = 0.5f*vg*(1.f + erff(vg*0.70710678118f));
        outG[(long)grow*4096 + gcol] = f2bf(va*ge);
      }
}

// ---------------- flash attention (pipelined, single-buf V, DPP softmax) ----------------
__global__ __launch_bounds__(256) void attn_kernel(const short* __restrict__ Q,
    const short* __restrict__ Kb, const short* __restrict__ Vb,
    float* __restrict__ interOut, short* __restrict__ attnB)
{
  __shared__ short Kt[2*64*64];   // 16 KiB dbuf (GLDS target)
  __shared__ short Vt[64*64];     //  8 KiB single buf, V^T [d][j] swizzled
  __shared__ short Pt[4*16*72];   //  9 KiB per-wave P tiles, padded
  const int t = threadIdx.x, w = t>>6, l = t&63;
  const int bid = blockIdx.x;
  const int nb = (bid & 7)*128 + (bid >> 3);   // XCD-chunked
  const int bh = nb >> 5;
  const int q0 = (nb & 31)*64;
  const int lr = l&15, lk = (l>>4)*8, g = l>>4;
  const long base = (long)bh * (N_*DH_);
  const int qrow = q0 + w*16;
  bh8 qf0 = *reinterpret_cast<const bh8*>(&Q[base + (long)(qrow+lr)*DH_ + lk]);
  bh8 qf1 = *reinterpret_cast<const bh8*>(&Q[base + (long)(qrow+lr)*DH_ + 32 + lk]);
  f4 o[4];
  #pragma unroll
  for (int i=0;i<4;i++) o[i]=f4{0.f,0.f,0.f,0.f};
  float m_run[4], l_run[4];
  #pragma unroll
  for (int r=0;r<4;r++){ m_run[r]=-1e30f; l_run[r]=0.f; }
  short* Pw = &Pt[w*16*72];
  const char* ldsK = (const char*)Kt;
  const int beta0 = w*2048 + l*16;
  const int srow = t>>3, sdp = t&7, sd = sdp*8;
  const int NT = N_/64;
  int4 vv[2];
  {  // prologue: tile-0 K GLDS + V loads
    const char* Kg = (const char*)(Kb + base);
    #pragma unroll
    for (int i=0;i<2;i++) {
      const int beta = beta0 + i*1024;
      const int krow = beta>>7, kpch = (beta>>4)&7;
      GLDS(Kg + krow*128 + (kpch ^ (krow&7))*16, (char*)Kt + (w*2+i)*1024);
    }
    #pragma unroll
    for (int it=0; it<2; it++)
      vv[it] = *reinterpret_cast<const int4*>(&Vb[base + (long)(it*32+srow)*DH_ + sd]);
  }
  for (int kt=0; kt<NT; kt++) {
    const int b = kt & 1;
    asm volatile("s_waitcnt vmcnt(0)" ::: "memory");  // tile-kt K in LDS, V in regs
    // write V regs -> Vt (single buf; prev readers done at last barrier)
    #pragma unroll
    for (int it=0; it<2; it++) {
      const short* vs = reinterpret_cast<const short*>(&vv[it]);
      const int cb0 = (it*4 + (srow>>3)) ^ sdp;
      const int jc  = srow & 7;
      #pragma unroll
      for (int e=0;e<8;e++)
        Vt[(sd+e)*64 + ((cb0^e)<<3) + jc] = vs[e];
    }
    // prefetch next tile (K GLDS -> other buf, V -> regs)
    if (kt+1 < NT) {
      const char* Kg = (const char*)(Kb + base + (long)(kt+1)*64*DH_);
      #pragma unroll
      for (int i=0;i<2;i++) {
        const int beta = beta0 + i*1024;
        const int krow = beta>>7, kpch = (beta>>4)&7;
        GLDS(Kg + krow*128 + (kpch ^ (krow&7))*16, (char*)Kt + (b^1)*8192 + (w*2+i)*1024);
      }
      #pragma unroll
      for (int it=0; it<2; it++)
        vv[it] = *reinterpret_cast<const int4*>(&Vb[base + (long)((kt+1)*64 + it*32+srow)*DH_ + sd]);
    }
    asm volatile("s_waitcnt lgkmcnt(0)" ::: "memory");
    __builtin_amdgcn_s_barrier();
    // S = Q K^T
    f4 s[4];
    __builtin_amdgcn_s_setprio(1);
    #pragma unroll
    for (int cb=0;cb<4;cb++) {
      const int krow = cb*16+lr;
      const char* kr = ldsK + b*8192 + krow*128;
      bh8 kf0 = *reinterpret_cast<const bh8*>(kr + ((g  )^(lr&7))*16);
      bh8 kf1 = *reinterpret_cast<const bh8*>(kr + ((g+4)^(lr&7))*16);
      f4 z = f4{0.f,0.f,0.f,0.f};
      z = MFMA16(qf0, kf0, z);
      z = MFMA16(qf1, kf1, z);
      s[cb] = z;
    }
    __builtin_amdgcn_s_setprio(0);
    // online softmax — DPP reductions over 16-lane row groups
    #pragma unroll
    for (int r=0;r<4;r++) {
      float mx = fmaxf(fmaxf(s[0][r],s[1][r]), fmaxf(s[2][r],s[3][r]));
      mx = dpp_max16(mx);
      const float mn = fmaxf(m_run[r], mx);
      const float al = __expf(m_run[r]-mn);
      m_run[r] = mn;
      float sum = 0.f;
      #pragma unroll
      for (int cb=0;cb<4;cb++) {
        const float pv = __expf(s[cb][r]-mn);
        sum += pv;
        Pw[((l>>4)*4 + r)*72 + cb*16 + lr] = f2bf(pv);
      }
      l_run[r] = l_run[r]*al + dpp_sum16(sum);
      #pragma unroll
      for (int cb=0;cb<4;cb++) o[cb][r] *= al;
    }
    // fence P write->read (wave-local)
    asm volatile("s_waitcnt lgkmcnt(0)" ::: "memory");
    __builtin_amdgcn_sched_barrier(0);
    bh8 pa0 = *reinterpret_cast<const bh8*>(&Pw[lr*72 + lk]);
    bh8 pa1 = *reinterpret_cast<const bh8*>(&Pw[lr*72 + 32 + lk]);
    // PV from swizzled Vt
    #pragma unroll
    for (int kk=0; kk<2; kk++) {
      const bh8 pa = kk ? pa1 : pa0;
      __builtin_amdgcn_s_setprio(1);
      #pragma unroll
      for (int db=0; db<4; db++) {
        const int dd = db*16 + lr;
        const int ch = (kk*4 + g) ^ (dd&7) ^ ((dd>>3)&7);
        bh8 vf = *reinterpret_cast<const bh8*>(&Vt[dd*64 + ch*8]);
        o[db] = MFMA16(pa, vf, o[db]);
      }
      __builtin_amdgcn_s_setprio(0);
    }
    __builtin_amdgcn_s_barrier();   // all waves done with Kt[b], Vt, Pt
  }
  const int bb = bh>>4, hh = bh&15;
  #pragma unroll
  for (int db=0; db<4; db++)
    #pragma unroll
    for (int r=0;r<4;r++) {
      const int n = qrow + (l>>4)*4 + r;
      const int d = db*16 + lr;
      const float v = o[db][r] / l_run[r];
      interOut[base + (long)n*DH_ + d] = v;
      attnB[(long)(bb*N_ + n)*1024 + hh*DH_ + d] = f2bf(v);
    }
}

extern "C" void kernel_launch(void* const* d_in, const int* in_sizes, int n_in,
                              void* d_out, int out_size, void* d_ws, size_t ws_size,
                              hipStream_t stream)
{
  const float* x    = (const float*)d_in[0];
  const float* Wq   = (const float*)d_in[1];
  const float* Wk   = (const float*)d_in[2];
  const float* Wv   = (const float*)d_in[3];
  const float* Wo   = (const float*)d_in[4];
  const float* bo   = (const float*)d_in[5];
  const float* ln1g = (const float*)d_in[6];
  const float* ln1b = (const float*)d_in[7];
  const float* ln3g = (const float*)d_in[8];
  const float* ln3b = (const float*)d_in[9];
  const float* Wff1 = (const float*)d_in[10];
  const float* bff1 = (const float*)d_in[11];
  const float* Wff2 = (const float*)d_in[12];
  const float* bff2 = (const float*)d_in[13];
  float* out = (float*)d_out;
  const long SZ = (long)M_*D_;
  float* out_x     = out;
  float* out_q     = out + SZ;
  float* out_k     = out + 2*SZ;
  float* out_v     = out + 3*SZ;
  float* out_inter = out + 4*SZ;
  float* out_xf    = out + 5*SZ;

  char* p = (char*)d_ws;
  auto alloc = [&](size_t bytes){ void* r = (void*)p; p += (bytes + 255) & ~(size_t)255; return r; };
  short* xf_bf  = (short*)alloc(SZ*2);
  short* q_bf   = (short*)alloc(SZ*2);
  short* k_bf   = (short*)alloc(SZ*2);
  short* v_bf   = (short*)alloc(SZ*2);
  short* at_bf  = (short*)alloc(SZ*2);
  float* x2     = (float*)alloc(SZ*4);
  short* x2n_bf = (short*)alloc(SZ*2);
  short* g_bf   = (short*)alloc((size_t)M_*4096*2);
  short* WqT    = (short*)alloc((size_t)1024*1024*2);
  short* WkT    = (short*)alloc((size_t)1024*1024*2);
  short* WvT    = (short*)alloc((size_t)1024*1024*2);
  short* WoT    = (short*)alloc((size_t)1024*1024*2);
  short* Wff1T  = (short*)alloc((size_t)8192*1024*2);
  short* Wff2T  = (short*)alloc((size_t)1024*4096*2);
  (void)in_sizes; (void)n_in; (void)out_size; (void)ws_size;

  dim3 blk(256);
  transpose_cast4<<<dim3(32,32,4), blk, 0, stream>>>(Wq, Wk, Wv, Wo, WqT, WkT, WvT, WoT);
  transpose_cast<<<dim3(256,32), blk, 0, stream>>>(Wff1, Wff1T, 1024, 8192);
  transpose_cast<<<dim3(32,128), blk, 0, stream>>>(Wff2, Wff2T, 4096, 1024);
  ln_kernel<<<M_, blk, 0, stream>>>(x, ln1g, ln1b, out_xf, xf_bf);
  gemm_qkv<<<dim3(32,24), blk, 0, stream>>>(xf_bf, WqT, WkT, WvT,
                                            out_q, out_k, out_v, q_bf, k_bf, v_bf);
  attn_kernel<<<1024, blk, 0, stream>>>(q_bf, k_bf, v_bf, out_inter, at_bf);
  gemm_bt<1,64><<<dim3(64,8),  blk, 0, stream>>>(at_bf,  WoT,   1024, 1024, bo,   x,   x2,    nullptr);
  ln_kernel<<<M_, blk, 0, stream>>>(x2, ln3g, ln3b, nullptr, x2n_bf);
  gemm_ff1<<<dim3(64,32), blk, 0, stream>>>(x2n_bf, Wff1T, bff1, g_bf);
  gemm_bt<1,64><<<dim3(64,8),  blk, 0, stream>>>(g_bf,   Wff2T, 1024, 4096, bff2, x2,  out_x, nullptr);
}